// Round 3
// baseline (268.413 us; speedup 1.0000x reference)
//
#include <hip/hip_runtime.h>

// MNIST_RNN R12: kill the gate-transpose LDS round-trip. R11 post-mortem:
// VALU cut landed (VALUBusy 35.7->29.9, conflicts -15%) but wall pinned
// ~142us -> not issue-bound; stall-dominated per-iteration serial DS
// chain. Largest removable segment: gbuf write->drain->read (gate
// transpose). Fix: 4 N-tiles of 10 gates (i/f/g/o at rows 10T+lm, lm<10)
// instead of 3x16 -> MFMA output lands at lane (q,u=lm) regs C[0..3][r]
// = i,f,g,o for samples 4q+r: act + c/h update in pure register
// dataflow. +6 MFMA/iter (MfmaUtil 4.7%, free); -14 DS ops, -1 FENCE
// drain, -act-select ops; gbuf GONE (LDS 15.4KB -> 7.4KB, enables
// future 16-block/CU probe). Numerics: same split/products; gate rows
// re-tiled only.

#define HDIM 10
#define DDIM 28
#define TSTEPS 28

typedef __attribute__((ext_vector_type(8))) short short8;
typedef __attribute__((ext_vector_type(4))) float f32x4;

__device__ __forceinline__ unsigned short bf16_rne(float f) {
    unsigned u = __builtin_bit_cast(unsigned, f);
    u += 0x7FFFu + ((u >> 16) & 1u);
    return (unsigned short)(u >> 16);
}
__device__ __forceinline__ float bf16_f(unsigned short h) {
    unsigned u = ((unsigned)h) << 16;
    return __builtin_bit_cast(float, u);
}
// packed {lo:hi} bf16 split of v: low16 = bf16_rne(v), high16 = bf16_rne(v - hi)
__device__ __forceinline__ unsigned pk_hl(float v) {
    unsigned a, p;
    const float z = 0.0f;
    asm("v_cvt_pk_bf16_f32 %0, %1, %2" : "=v"(a) : "v"(v), "v"(z));
    const float hif = __builtin_bit_cast(float, a << 16);
    const float d = v - hif;
    asm("v_cvt_pk_bf16_f32 %0, %1, %2" : "=v"(p) : "v"(v), "v"(d));
    return p;
}
__device__ __forceinline__ float sig_f(float v) {
    return __builtin_amdgcn_rcpf(1.0f + __expf(-v));
}
__device__ __forceinline__ float tanh_f(float v) {
    return 2.0f * __builtin_amdgcn_rcpf(1.0f + __expf(-2.0f * v)) - 1.0f;
}

#define FENCE() __asm volatile("" ::: "memory")
#define WR32(arrp, sidx, val) (*(unsigned*)&(arrp)[(sidx)] = (val))

__global__ __launch_bounds__(64) void lstm2_mfma_kernel(
    const float* __restrict__ x,
    const float* __restrict__ w_ih0, const float* __restrict__ w_hh0,
    const float* __restrict__ b_ih0, const float* __restrict__ b_hh0,
    const float* __restrict__ w_ih1, const float* __restrict__ w_hh1,
    const float* __restrict__ b_ih1, const float* __restrict__ b_hh1,
    const float* __restrict__ w_cls, const float* __restrict__ b_cls,
    float* __restrict__ out)
{
    // A0 row (stride 136 shorts): [ (x_d hi,lo) pairs d<28 : cols 0..55 |
    //   (h0_u hi,lo) pairs u<10 : 56..75 | x_d hi : 76..103 |
    //   h0_u hi : 104..113 | pad 114..135 ]
    // A1 row (stride 72): [ (h0 hi,lo) 0..19 | (h1 hi,lo) 20..39 |
    //   h0 hi 40..49 | h1 hi 50..59 | pad 60..71 ]
    __shared__ unsigned short uA0[16 * 136];
    __shared__ unsigned short uA1[16 * 72];
    __shared__ float hfin[16 * 12];

    const int l  = threadIdx.x;
    const int lm = l & 15;
    const int q  = l >> 4;
    const int sbase = blockIdx.x * 16;

    // ---- zero A-panel pads (NaN*0=NaN in MFMA) ----
    for (int i = l; i < 16 * 22; i += 64) uA0[(i / 22) * 136 + 114 + (i % 22)] = 0;
    for (int i = l; i < 16 * 12; i += 64) uA1[(i / 12) * 72 + 60 + (i % 12)] = 0;

    // ---- build B-fragments in registers (once) ----
    // 4 N-tiles: tile T row lm = gate g = 10T+lm (lm<10; rows lm>=10 zero).
    // T=0:i, T=1:f, T=2:g, T=3:o (torch gate order).
    // B0 k-zones: kk<76 pair zone -> w_hi (j2=kk>>1); [76,114) -> w_lo.
    // B1 k-zones: kk<40 pair zone -> w_hi; [40,60) -> w_lo.
    short8 B0[4][4], B1[4][2];
    const bool gvalid = (lm < 10);
    #pragma unroll
    for (int T = 0; T < 4; ++T) {
        const int g = 10 * T + lm;
        #pragma unroll
        for (int c = 0; c < 4; ++c) {
            #pragma unroll
            for (int j = 0; j < 8; ++j) {
                const int kk = 32 * c + 8 * q + j;
                unsigned short bits = 0;
                if (gvalid && kk < 114) {
                    if (kk < 76) {
                        const int j2 = kk >> 1;
                        const float w = (j2 < 28) ? w_ih0[g * 28 + j2]
                                                  : w_hh0[g * 10 + (j2 - 28)];
                        bits = bf16_rne(w);
                    } else {
                        const int d = kk - 76;
                        const float w = (d < 28) ? w_ih0[g * 28 + d]
                                                 : w_hh0[g * 10 + (d - 28)];
                        const unsigned short hi = bf16_rne(w);
                        bits = bf16_rne(w - bf16_f(hi));
                    }
                }
                B0[T][c][j] = (short)bits;
            }
        }
        #pragma unroll
        for (int c = 0; c < 2; ++c) {
            #pragma unroll
            for (int j = 0; j < 8; ++j) {
                const int kk = 32 * c + 8 * q + j;
                unsigned short bits = 0;
                if (gvalid && kk < 60) {
                    if (kk < 40) {
                        const int j2 = kk >> 1;
                        const float w = (j2 < 10) ? w_ih1[g * 10 + j2]
                                                  : w_hh1[g * 10 + (j2 - 10)];
                        bits = bf16_rne(w);
                    } else {
                        const int d = kk - 40;
                        const float w = (d < 10) ? w_ih1[g * 10 + d]
                                                 : w_hh1[g * 10 + (d - 10)];
                        const unsigned short hi = bf16_rne(w);
                        bits = bf16_rne(w - bf16_f(hi));
                    }
                }
                B1[T][c][j] = (short)bits;
            }
        }
    }

    // biases folded into MFMA C-init
    float bias0[4], bias1[4];
    #pragma unroll
    for (int T = 0; T < 4; ++T) {
        const int g = 10 * T + lm;
        bias0[T] = gvalid ? (b_ih0[g] + b_hh0[g]) : 0.0f;
        bias1[T] = gvalid ? (b_ih1[g] + b_hh1[g]) : 0.0f;
    }

    // ---- x pipeline: lane owns 7 of the 448 (sample,d) elements ----
    int xoff[7], lofsA[7], lofsB[7]; float xn[7];
    #pragma unroll
    for (int i = 0; i < 7; ++i) {
        const int f = l + 64 * i;
        const int sm = f / 28, d = f - 28 * sm;
        lofsA[i] = sm * 136 + 2 * d;        // b32 (pair zone)
        lofsB[i] = sm * 136 + 76 + d;       // b16 (hi zone)
        xoff[i] = (sbase + sm) * (TSTEPS * DDIM) + d;
        xn[i] = x[xoff[i]];                 // t = 0
    }
    #pragma unroll
    for (int i = 0; i < 7; ++i) {
        const unsigned p = pk_hl(xn[i]);
        WR32(uA0, lofsA[i], p);
        uA0[lofsB[i]] = (unsigned short)p;
    }
    // zero h zones (h0 = h1 = 0 at t=0)
    if (lm < 10) {
        #pragma unroll
        for (int r = 0; r < 4; ++r) {
            const int m = 4 * q + r;
            unsigned short* r0 = &uA0[m * 136];
            WR32(r0, 56 + 2 * lm, 0u); r0[104 + lm] = 0;
            unsigned short* r1 = &uA1[m * 72];
            WR32(r1, 2 * lm, 0u);      r1[40 + lm] = 0;   // h0
            WR32(r1, 20 + 2 * lm, 0u); r1[50 + lm] = 0;   // h1
        }
    }
    FENCE();

    float c0s[4] = {0, 0, 0, 0}, c1s[4] = {0, 0, 0, 0};
    float h1v[4] = {0, 0, 0, 0};
    float h0v[4];
    short8 A0f[4], A1f[2];

    // ================= prologue: cell0(0) =================
    #pragma unroll
    for (int c = 0; c < 4; ++c)
        A0f[c] = *(const short8*)&uA0[lm * 136 + 32 * c + 8 * q];
    FENCE();
    #pragma unroll
    for (int i = 0; i < 7; ++i) { xoff[i] += DDIM; xn[i] = x[xoff[i]]; }  // x(1)
    {
        f32x4 C[4];
        #pragma unroll
        for (int T = 0; T < 4; ++T) {
            f32x4 acc = {bias0[T], bias0[T], bias0[T], bias0[T]};
            #pragma unroll
            for (int c = 0; c < 4; ++c)
                acc = __builtin_amdgcn_mfma_f32_16x16x32_bf16(A0f[c], B0[T][c], acc, 0, 0, 0);
            C[T] = acc;
        }
        // act + update in registers: lane (q, u=lm) holds samples m=4q+r
        #pragma unroll
        for (int r = 0; r < 4; ++r) {
            const float i0 = sig_f(C[0][r]);
            const float f0 = sig_f(C[1][r]);
            const float g0 = tanh_f(C[2][r]);
            const float o0 = sig_f(C[3][r]);
            const float c0 = f0 * c0s[r] + i0 * g0;
            c0s[r] = c0;
            h0v[r] = o0 * tanh_f(c0);
        }
        if (lm < 10) {
            #pragma unroll
            for (int r = 0; r < 4; ++r) {
                const int m = 4 * q + r;
                const unsigned p0 = pk_hl(h0v[r]);
                unsigned short* r0 = &uA0[m * 136];
                WR32(r0, 56 + 2 * lm, p0); r0[104 + lm] = (unsigned short)p0;
                unsigned short* r1 = &uA1[m * 72];
                WR32(r1, 2 * lm, p0);      r1[40 + lm] = (unsigned short)p0;
            }
        }
        // write x(1)
        #pragma unroll
        for (int i = 0; i < 7; ++i) {
            const unsigned p = pk_hl(xn[i]);
            WR32(uA0, lofsA[i], p);
            uA0[lofsB[i]] = (unsigned short)p;
        }
    }
    FENCE();

    // ===== main loop: iteration t computes cell1(t) AND cell0(t+1) =====
    #pragma unroll 1
    for (int t = 0; t < TSTEPS - 1; ++t) {
        // ---- read phase: A1 = {h0(t), h1(t-1)}, A0 = {x(t+1), h0(t)} ----
        #pragma unroll
        for (int c = 0; c < 2; ++c)
            A1f[c] = *(const short8*)&uA1[lm * 72 + 32 * c + 8 * q];
        #pragma unroll
        for (int c = 0; c < 4; ++c)
            A0f[c] = *(const short8*)&uA0[lm * 136 + 32 * c + 8 * q];
        FENCE();

        // prefetch x(t+2)
        if (t < TSTEPS - 2) {
            #pragma unroll
            for (int i = 0; i < 7; ++i) { xoff[i] += DDIM; xn[i] = x[xoff[i]]; }
        }

        // ---- MFMA phase: 8 independent accumulator chains (24 MFMA) ----
        f32x4 C[4], D[4];
        #pragma unroll
        for (int T = 0; T < 4; ++T) {
            f32x4 accD = {bias1[T], bias1[T], bias1[T], bias1[T]};
            #pragma unroll
            for (int c = 0; c < 2; ++c)
                accD = __builtin_amdgcn_mfma_f32_16x16x32_bf16(A1f[c], B1[T][c], accD, 0, 0, 0);
            D[T] = accD;
            f32x4 accC = {bias0[T], bias0[T], bias0[T], bias0[T]};
            #pragma unroll
            for (int c = 0; c < 4; ++c)
                accC = __builtin_amdgcn_mfma_f32_16x16x32_bf16(A0f[c], B0[T][c], accC, 0, 0, 0);
            C[T] = accC;
        }

        // ---- act + update: pure register dataflow, no LDS transpose ----
        #pragma unroll
        for (int r = 0; r < 4; ++r) {
            const float i1 = sig_f(D[0][r]);
            const float f1 = sig_f(D[1][r]);
            const float g1 = tanh_f(D[2][r]);
            const float o1 = sig_f(D[3][r]);
            const float c1 = f1 * c1s[r] + i1 * g1;
            c1s[r] = c1;
            h1v[r] = o1 * tanh_f(c1);
            const float i0 = sig_f(C[0][r]);
            const float f0 = sig_f(C[1][r]);
            const float g0 = tanh_f(C[2][r]);
            const float o0 = sig_f(C[3][r]);
            const float c0 = f0 * c0s[r] + i0 * g0;
            c0s[r] = c0;
            h0v[r] = o0 * tanh_f(c0);
        }

        // ---- write phase: h1(t), h0(t+1), x(t+2) ----
        if (lm < 10) {
            #pragma unroll
            for (int r = 0; r < 4; ++r) {
                const int m = 4 * q + r;
                const unsigned p1 = pk_hl(h1v[r]);
                unsigned short* r1 = &uA1[m * 72];
                WR32(r1, 20 + 2 * lm, p1); r1[50 + lm] = (unsigned short)p1;
                const unsigned p0 = pk_hl(h0v[r]);
                WR32(r1, 2 * lm, p0);      r1[40 + lm] = (unsigned short)p0;
                unsigned short* r0 = &uA0[m * 136];
                WR32(r0, 56 + 2 * lm, p0); r0[104 + lm] = (unsigned short)p0;
            }
        }
        if (t < TSTEPS - 2) {
            #pragma unroll
            for (int i = 0; i < 7; ++i) {
                const unsigned p = pk_hl(xn[i]);
                WR32(uA0, lofsA[i], p);
                uA0[lofsB[i]] = (unsigned short)p;
            }
        }
        FENCE();
    }

    // ================= epilogue: cell1(27), all in registers =================
    {
        #pragma unroll
        for (int c = 0; c < 2; ++c)
            A1f[c] = *(const short8*)&uA1[lm * 72 + 32 * c + 8 * q];
        FENCE();
        f32x4 D[4];
        #pragma unroll
        for (int T = 0; T < 4; ++T) {
            f32x4 acc = {bias1[T], bias1[T], bias1[T], bias1[T]};
            #pragma unroll
            for (int c = 0; c < 2; ++c)
                acc = __builtin_amdgcn_mfma_f32_16x16x32_bf16(A1f[c], B1[T][c], acc, 0, 0, 0);
            D[T] = acc;
        }
        #pragma unroll
        for (int r = 0; r < 4; ++r) {
            const float i1 = sig_f(D[0][r]);
            const float f1 = sig_f(D[1][r]);
            const float g1 = tanh_f(D[2][r]);
            const float o1 = sig_f(D[3][r]);
            const float c1 = f1 * c1s[r] + i1 * g1;
            h1v[r] = o1 * tanh_f(c1);
        }
    }

    // ---- classifier ----
    if (lm < 10) {
        #pragma unroll
        for (int r = 0; r < 4; ++r) hfin[(4 * q + r) * 12 + lm] = h1v[r];
    }
    FENCE();
    if (lm < 10) {
        float wc[10];
        #pragma unroll
        for (int j = 0; j < 10; ++j) wc[j] = w_cls[lm * 10 + j];
        const float bo = b_cls[lm];
        #pragma unroll
        for (int r = 0; r < 4; ++r) {
            const int m = 4 * q + r;
            float acc = bo;
            #pragma unroll
            for (int j = 0; j < 10; ++j) acc += hfin[m * 12 + j] * wc[j];
            out[(size_t)(sbase + m) * 10 + lm] = acc;
        }
    }
}

extern "C" void kernel_launch(void* const* d_in, const int* in_sizes, int n_in,
                              void* d_out, int out_size, void* d_ws, size_t ws_size,
                              hipStream_t stream) {
    const float* x     = (const float*)d_in[0];
    const float* w_ih0 = (const float*)d_in[1];
    const float* w_hh0 = (const float*)d_in[2];
    const float* b_ih0 = (const float*)d_in[3];
    const float* b_hh0 = (const float*)d_in[4];
    const float* w_ih1 = (const float*)d_in[5];
    const float* w_hh1 = (const float*)d_in[6];
    const float* b_ih1 = (const float*)d_in[7];
    const float* b_hh1 = (const float*)d_in[8];
    const float* w_cls = (const float*)d_in[9];
    const float* b_cls = (const float*)d_in[10];
    float* out = (float*)d_out;

    const int B = in_sizes[0] / (TSTEPS * DDIM);   // 32768
    const int grid = B / 16;                       // 2048 blocks of 1 wave

    hipLaunchKernelGGL(lstm2_mfma_kernel, dim3(grid), dim3(64), 0, stream,
                       x, w_ih0, w_hh0, b_ih0, b_hh0,
                       w_ih1, w_hh1, b_ih1, b_hh1,
                       w_cls, b_cls, out);
}

// Round 4
// 265.751 us; speedup vs baseline: 1.0100x; 1.0100x over previous
//
#include <hip/hip_runtime.h>

// MNIST_RNN R13: discriminating probe. R10 (pipeline merge): null. R11
// (-15% VALU): null. R12 (gate transpose removed, -DS): -10us REGRESSION
// despite conflicts -35% -> wall is NOT instruction-stream-bound; ~10x
// gap between critical-path estimate (~600cyc/iter) and measured wall
// (~13k cyc/iter). Untested external suspects, both probed here:
//  (1) RESIDENCY: Occupancy~11% => ~3.5 waves/CU avg vs 8 launched.
//      Fix: 4 private waves per 256-thread block (512 blocks), forcing
//      co-residency. No barriers; per-wave LDS slices.
//  (2) X-LOAD LATENCY: loads issued+consumed in same iteration under
//      2048-wave lockstep burst congestion. Fix: depth-2 prefetch via
//      role-alternating buffers (unroll-by-2, no reg copies): issue
//      x(t+3) at iter t, consume at t+1 (~13k cycle distance).
// Decision tree: occupancy up & dur ~85 -> residency was wall; dur -20
// only -> x-latency; both null -> R14 = operand-swap rewrite (no LDS in
// recurrence). Numerics identical to R12.

#define HDIM 10
#define DDIM 28
#define TSTEPS 28

typedef __attribute__((ext_vector_type(8))) short short8;
typedef __attribute__((ext_vector_type(4))) float f32x4;

__device__ __forceinline__ unsigned short bf16_rne(float f) {
    unsigned u = __builtin_bit_cast(unsigned, f);
    u += 0x7FFFu + ((u >> 16) & 1u);
    return (unsigned short)(u >> 16);
}
__device__ __forceinline__ float bf16_f(unsigned short h) {
    unsigned u = ((unsigned)h) << 16;
    return __builtin_bit_cast(float, u);
}
// packed {lo:hi} bf16 split of v: low16 = bf16_rne(v), high16 = bf16_rne(v - hi)
__device__ __forceinline__ unsigned pk_hl(float v) {
    unsigned a, p;
    const float z = 0.0f;
    asm("v_cvt_pk_bf16_f32 %0, %1, %2" : "=v"(a) : "v"(v), "v"(z));
    const float hif = __builtin_bit_cast(float, a << 16);
    const float d = v - hif;
    asm("v_cvt_pk_bf16_f32 %0, %1, %2" : "=v"(p) : "v"(v), "v"(d));
    return p;
}
__device__ __forceinline__ float sig_f(float v) {
    return __builtin_amdgcn_rcpf(1.0f + __expf(-v));
}
__device__ __forceinline__ float tanh_f(float v) {
    return 2.0f * __builtin_amdgcn_rcpf(1.0f + __expf(-2.0f * v)) - 1.0f;
}

#define FENCE() __asm volatile("" ::: "memory")
#define WR32(arrp, sidx, val) (*(unsigned*)&(arrp)[(sidx)] = (val))

// one LSTM macro-iteration: computes cell1(T) and cell0(T+1).
// P holds x(T+2) (fully loaded, issued one iteration ago); Q receives
// the x(T+3) load issue. P is written to LDS at the end of the body.
#define BODY(P, Q, T) do {                                                    \
    _Pragma("unroll")                                                         \
    for (int c = 0; c < 2; ++c)                                               \
        A1f[c] = *(const short8*)&uA1w[lm * 72 + 32 * c + 8 * q];             \
    _Pragma("unroll")                                                         \
    for (int c = 0; c < 4; ++c)                                               \
        A0f[c] = *(const short8*)&uA0w[lm * 136 + 32 * c + 8 * q];            \
    FENCE();                                                                  \
    if ((T) < TSTEPS - 3) {                                                   \
        _Pragma("unroll")                                                     \
        for (int i = 0; i < 7; ++i) { xoff[i] += DDIM; Q[i] = x[xoff[i]]; }   \
    }                                                                         \
    f32x4 C[4], D[4];                                                         \
    _Pragma("unroll")                                                         \
    for (int T4 = 0; T4 < 4; ++T4) {                                          \
        f32x4 accD = {bias1[T4], bias1[T4], bias1[T4], bias1[T4]};            \
        _Pragma("unroll")                                                     \
        for (int c = 0; c < 2; ++c)                                           \
            accD = __builtin_amdgcn_mfma_f32_16x16x32_bf16(A1f[c], B1[T4][c], accD, 0, 0, 0); \
        D[T4] = accD;                                                         \
        f32x4 accC = {bias0[T4], bias0[T4], bias0[T4], bias0[T4]};            \
        _Pragma("unroll")                                                     \
        for (int c = 0; c < 4; ++c)                                           \
            accC = __builtin_amdgcn_mfma_f32_16x16x32_bf16(A0f[c], B0[T4][c], accC, 0, 0, 0); \
        C[T4] = accC;                                                         \
    }                                                                         \
    _Pragma("unroll")                                                         \
    for (int r = 0; r < 4; ++r) {                                             \
        const float i1 = sig_f(D[0][r]);                                      \
        const float f1 = sig_f(D[1][r]);                                      \
        const float g1 = tanh_f(D[2][r]);                                     \
        const float o1 = sig_f(D[3][r]);                                      \
        const float c1 = f1 * c1s[r] + i1 * g1;                               \
        c1s[r] = c1;                                                          \
        h1v[r] = o1 * tanh_f(c1);                                             \
        const float i0 = sig_f(C[0][r]);                                      \
        const float f0 = sig_f(C[1][r]);                                      \
        const float g0 = tanh_f(C[2][r]);                                     \
        const float o0 = sig_f(C[3][r]);                                      \
        const float c0 = f0 * c0s[r] + i0 * g0;                               \
        c0s[r] = c0;                                                          \
        h0v[r] = o0 * tanh_f(c0);                                             \
    }                                                                         \
    if ((T) < TSTEPS - 2) {                                                   \
        _Pragma("unroll")                                                     \
        for (int i = 0; i < 7; ++i) {                                         \
            const unsigned p = pk_hl(P[i]);                                   \
            WR32(uA0w, lofsA[i], p);                                          \
            uA0w[lofsB[i]] = (unsigned short)p;                               \
        }                                                                     \
    }                                                                         \
    if (lm < 10) {                                                            \
        _Pragma("unroll")                                                     \
        for (int r = 0; r < 4; ++r) {                                         \
            const int m = 4 * q + r;                                          \
            const unsigned p1 = pk_hl(h1v[r]);                                \
            unsigned short* r1 = &uA1w[m * 72];                               \
            WR32(r1, 20 + 2 * lm, p1); r1[50 + lm] = (unsigned short)p1;      \
            const unsigned p0 = pk_hl(h0v[r]);                                \
            WR32(r1, 2 * lm, p0);      r1[40 + lm] = (unsigned short)p0;      \
            unsigned short* r0 = &uA0w[m * 136];                              \
            WR32(r0, 56 + 2 * lm, p0); r0[104 + lm] = (unsigned short)p0;     \
        }                                                                     \
    }                                                                         \
    FENCE();                                                                  \
} while (0)

__global__ __launch_bounds__(256) void lstm2_mfma_kernel(
    const float* __restrict__ x,
    const float* __restrict__ w_ih0, const float* __restrict__ w_hh0,
    const float* __restrict__ b_ih0, const float* __restrict__ b_hh0,
    const float* __restrict__ w_ih1, const float* __restrict__ w_hh1,
    const float* __restrict__ b_ih1, const float* __restrict__ b_hh1,
    const float* __restrict__ w_cls, const float* __restrict__ b_cls,
    float* __restrict__ out)
{
    // 4 independent waves per block; per-wave private LDS slices, no barriers.
    // A0 row (stride 136 shorts): [ (x_d hi,lo) pairs d<28 : cols 0..55 |
    //   (h0_u hi,lo) pairs u<10 : 56..75 | x_d hi : 76..103 |
    //   h0_u hi : 104..113 | pad 114..135 ]
    // A1 row (stride 72): [ (h0 hi,lo) 0..19 | (h1 hi,lo) 20..39 |
    //   h0 hi 40..49 | h1 hi 50..59 | pad 60..71 ]
    __shared__ __align__(16) unsigned short uA0s[4][16 * 136];
    __shared__ __align__(16) unsigned short uA1s[4][16 * 72];
    __shared__ __align__(16) float hfins[4][16 * 12];

    const int l   = threadIdx.x & 63;       // lane within wave
    const int wid = threadIdx.x >> 6;       // wave id in block
    const int lm  = l & 15;
    const int q   = l >> 4;
    const int sbase = (blockIdx.x * 4 + wid) * 16;

    unsigned short* const uA0w = uA0s[wid];
    unsigned short* const uA1w = uA1s[wid];
    float* const hfinw = hfins[wid];

    // ---- zero A-panel pads (NaN*0=NaN in MFMA) ----
    for (int i = l; i < 16 * 22; i += 64) uA0w[(i / 22) * 136 + 114 + (i % 22)] = 0;
    for (int i = l; i < 16 * 12; i += 64) uA1w[(i / 12) * 72 + 60 + (i % 12)] = 0;

    // ---- build B-fragments in registers (once) ----
    // 4 N-tiles: tile T row lm = gate g = 10T+lm (lm<10; rows lm>=10 zero).
    // T=0:i, T=1:f, T=2:g, T=3:o (torch gate order).
    // B0 k-zones: kk<76 pair zone -> w_hi (j2=kk>>1); [76,114) -> w_lo.
    // B1 k-zones: kk<40 pair zone -> w_hi; [40,60) -> w_lo.
    short8 B0[4][4], B1[4][2];
    const bool gvalid = (lm < 10);
    #pragma unroll
    for (int T = 0; T < 4; ++T) {
        const int g = 10 * T + lm;
        #pragma unroll
        for (int c = 0; c < 4; ++c) {
            #pragma unroll
            for (int j = 0; j < 8; ++j) {
                const int kk = 32 * c + 8 * q + j;
                unsigned short bits = 0;
                if (gvalid && kk < 114) {
                    if (kk < 76) {
                        const int j2 = kk >> 1;
                        const float w = (j2 < 28) ? w_ih0[g * 28 + j2]
                                                  : w_hh0[g * 10 + (j2 - 28)];
                        bits = bf16_rne(w);
                    } else {
                        const int d = kk - 76;
                        const float w = (d < 28) ? w_ih0[g * 28 + d]
                                                 : w_hh0[g * 10 + (d - 28)];
                        const unsigned short hi = bf16_rne(w);
                        bits = bf16_rne(w - bf16_f(hi));
                    }
                }
                B0[T][c][j] = (short)bits;
            }
        }
        #pragma unroll
        for (int c = 0; c < 2; ++c) {
            #pragma unroll
            for (int j = 0; j < 8; ++j) {
                const int kk = 32 * c + 8 * q + j;
                unsigned short bits = 0;
                if (gvalid && kk < 60) {
                    if (kk < 40) {
                        const int j2 = kk >> 1;
                        const float w = (j2 < 10) ? w_ih1[g * 10 + j2]
                                                  : w_hh1[g * 10 + (j2 - 10)];
                        bits = bf16_rne(w);
                    } else {
                        const int d = kk - 40;
                        const float w = (d < 10) ? w_ih1[g * 10 + d]
                                                 : w_hh1[g * 10 + (d - 10)];
                        const unsigned short hi = bf16_rne(w);
                        bits = bf16_rne(w - bf16_f(hi));
                    }
                }
                B1[T][c][j] = (short)bits;
            }
        }
    }

    // biases folded into MFMA C-init
    float bias0[4], bias1[4];
    #pragma unroll
    for (int T = 0; T < 4; ++T) {
        const int g = 10 * T + lm;
        bias0[T] = gvalid ? (b_ih0[g] + b_hh0[g]) : 0.0f;
        bias1[T] = gvalid ? (b_ih1[g] + b_hh1[g]) : 0.0f;
    }

    // ---- x pipeline: lane owns 7 of the wave's 448 (sample,d) elements ----
    int xoff[7], lofsA[7], lofsB[7];
    float xA[7], xB[7];
    #pragma unroll
    for (int i = 0; i < 7; ++i) {
        const int f = l + 64 * i;
        const int sm = f / 28, d = f - 28 * sm;
        lofsA[i] = sm * 136 + 2 * d;        // b32 (pair zone)
        lofsB[i] = sm * 136 + 76 + d;       // b16 (hi zone)
        xoff[i] = (sbase + sm) * (TSTEPS * DDIM) + d;
        xA[i] = x[xoff[i]];                 // t = 0
    }
    #pragma unroll
    for (int i = 0; i < 7; ++i) {
        const unsigned p = pk_hl(xA[i]);
        WR32(uA0w, lofsA[i], p);
        uA0w[lofsB[i]] = (unsigned short)p;
    }
    // zero h zones (h0 = h1 = 0 at t=0)
    if (lm < 10) {
        #pragma unroll
        for (int r = 0; r < 4; ++r) {
            const int m = 4 * q + r;
            unsigned short* r0 = &uA0w[m * 136];
            WR32(r0, 56 + 2 * lm, 0u); r0[104 + lm] = 0;
            unsigned short* r1 = &uA1w[m * 72];
            WR32(r1, 2 * lm, 0u);      r1[40 + lm] = 0;   // h0
            WR32(r1, 20 + 2 * lm, 0u); r1[50 + lm] = 0;   // h1
        }
    }
    FENCE();

    float c0s[4] = {0, 0, 0, 0}, c1s[4] = {0, 0, 0, 0};
    float h1v[4] = {0, 0, 0, 0};
    float h0v[4];
    short8 A0f[4], A1f[2];

    // issue x(1) -> xA (consumed at end of prologue)
    #pragma unroll
    for (int i = 0; i < 7; ++i) { xoff[i] += DDIM; xA[i] = x[xoff[i]]; }

    // ================= prologue: cell0(0) =================
    #pragma unroll
    for (int c = 0; c < 4; ++c)
        A0f[c] = *(const short8*)&uA0w[lm * 136 + 32 * c + 8 * q];
    FENCE();
    // issue x(2) -> xB (consumed at end of main-loop body t=0)
    #pragma unroll
    for (int i = 0; i < 7; ++i) { xoff[i] += DDIM; xB[i] = x[xoff[i]]; }
    {
        f32x4 C[4];
        #pragma unroll
        for (int T = 0; T < 4; ++T) {
            f32x4 acc = {bias0[T], bias0[T], bias0[T], bias0[T]};
            #pragma unroll
            for (int c = 0; c < 4; ++c)
                acc = __builtin_amdgcn_mfma_f32_16x16x32_bf16(A0f[c], B0[T][c], acc, 0, 0, 0);
            C[T] = acc;
        }
        #pragma unroll
        for (int r = 0; r < 4; ++r) {
            const float i0 = sig_f(C[0][r]);
            const float f0 = sig_f(C[1][r]);
            const float g0 = tanh_f(C[2][r]);
            const float o0 = sig_f(C[3][r]);
            const float c0 = f0 * c0s[r] + i0 * g0;
            c0s[r] = c0;
            h0v[r] = o0 * tanh_f(c0);
        }
        if (lm < 10) {
            #pragma unroll
            for (int r = 0; r < 4; ++r) {
                const int m = 4 * q + r;
                const unsigned p0 = pk_hl(h0v[r]);
                unsigned short* r0 = &uA0w[m * 136];
                WR32(r0, 56 + 2 * lm, p0); r0[104 + lm] = (unsigned short)p0;
                unsigned short* r1 = &uA1w[m * 72];
                WR32(r1, 2 * lm, p0);      r1[40 + lm] = (unsigned short)p0;
            }
        }
        // write x(1) (xA loads issued well before)
        #pragma unroll
        for (int i = 0; i < 7; ++i) {
            const unsigned p = pk_hl(xA[i]);
            WR32(uA0w, lofsA[i], p);
            uA0w[lofsB[i]] = (unsigned short)p;
        }
    }
    FENCE();

    // ===== main loop: body t computes cell1(t) and cell0(t+1); x buffers
    // alternate roles so each load is consumed one full iteration later =====
    #pragma unroll 1
    for (int tp = 0; tp < 13; ++tp) {
        BODY(xB, xA, 2 * tp);
        BODY(xA, xB, 2 * tp + 1);
    }
    BODY(xB, xA, 26);

    // ================= epilogue: cell1(27), all in registers =================
    {
        #pragma unroll
        for (int c = 0; c < 2; ++c)
            A1f[c] = *(const short8*)&uA1w[lm * 72 + 32 * c + 8 * q];
        FENCE();
        f32x4 D[4];
        #pragma unroll
        for (int T = 0; T < 4; ++T) {
            f32x4 acc = {bias1[T], bias1[T], bias1[T], bias1[T]};
            #pragma unroll
            for (int c = 0; c < 2; ++c)
                acc = __builtin_amdgcn_mfma_f32_16x16x32_bf16(A1f[c], B1[T][c], acc, 0, 0, 0);
            D[T] = acc;
        }
        #pragma unroll
        for (int r = 0; r < 4; ++r) {
            const float i1 = sig_f(D[0][r]);
            const float f1 = sig_f(D[1][r]);
            const float g1 = tanh_f(D[2][r]);
            const float o1 = sig_f(D[3][r]);
            const float c1 = f1 * c1s[r] + i1 * g1;
            h1v[r] = o1 * tanh_f(c1);
        }
    }

    // ---- classifier ----
    if (lm < 10) {
        #pragma unroll
        for (int r = 0; r < 4; ++r) hfinw[(4 * q + r) * 12 + lm] = h1v[r];
    }
    FENCE();
    if (lm < 10) {
        float wc[10];
        #pragma unroll
        for (int j = 0; j < 10; ++j) wc[j] = w_cls[lm * 10 + j];
        const float bo = b_cls[lm];
        #pragma unroll
        for (int r = 0; r < 4; ++r) {
            const int m = 4 * q + r;
            float acc = bo;
            #pragma unroll
            for (int j = 0; j < 10; ++j) acc += hfinw[m * 12 + j] * wc[j];
            out[(size_t)(sbase + m) * 10 + lm] = acc;
        }
    }
}

extern "C" void kernel_launch(void* const* d_in, const int* in_sizes, int n_in,
                              void* d_out, int out_size, void* d_ws, size_t ws_size,
                              hipStream_t stream) {
    const float* x     = (const float*)d_in[0];
    const float* w_ih0 = (const float*)d_in[1];
    const float* w_hh0 = (const float*)d_in[2];
    const float* b_ih0 = (const float*)d_in[3];
    const float* b_hh0 = (const float*)d_in[4];
    const float* w_ih1 = (const float*)d_in[5];
    const float* w_hh1 = (const float*)d_in[6];
    const float* b_ih1 = (const float*)d_in[7];
    const float* b_hh1 = (const float*)d_in[8];
    const float* w_cls = (const float*)d_in[9];
    const float* b_cls = (const float*)d_in[10];
    float* out = (float*)d_out;

    const int B = in_sizes[0] / (TSTEPS * DDIM);   // 32768
    const int grid = B / 64;                       // 512 blocks of 4 waves

    hipLaunchKernelGGL(lstm2_mfma_kernel, dim3(grid), dim3(256), 0, stream,
                       x, w_ih0, w_hh0, b_ih0, b_hh0,
                       w_ih1, w_hh1, b_ih1, b_hh1,
                       w_cls, b_cls, out);
}

// Round 6
// 232.867 us; speedup vs baseline: 1.1526x; 1.1412x over previous
//
#include <hip/hip_runtime.h>

// MNIST_RNN R14b: RETRY of R14 (bench infra failed twice; kernel never
// ran). Theory unchanged: across R9-R13 the wall (142-153us) is
// invariant to VALU count, DS count, MFMA count, serial segments, WG
// count, and prefetch depth — but every round ran exactly 2048 waves.
// dur/waves ~= 71ns/wave; occupancy ~11% of slots ~= 900 resident ~=
// streaming feed, not co-resident execution. Theory: wall ~ wave count.
// Probe+win: 32 samples/wave (two M-tiles sharing B-frags) -> 1024
// waves, 2x work/wave, same total issue, per-iteration fixed costs
// amortized 2x. 2 waves/block (512 blocks, 128 thr), LDS 29.7KB/block.
// __launch_bounds__(128,1): VGPR budget 512 (est ~330; at 1024 waves
// the cap is 4 waves/CU anyway, so >256 VGPR is free).
// Decision: ~85us -> wave-feed floor confirmed; ~105 -> amortization;
// ~145 null -> total-issue bound; >165 -> spill (check VGPR_Count).
// Numerics identical per cell to R12/R13.

#define HDIM 10
#define DDIM 28
#define TSTEPS 28
#define NX 14          // x elements per lane (32*28/64)

typedef __attribute__((ext_vector_type(8))) short short8;
typedef __attribute__((ext_vector_type(4))) float f32x4;

__device__ __forceinline__ unsigned short bf16_rne(float f) {
    unsigned u = __builtin_bit_cast(unsigned, f);
    u += 0x7FFFu + ((u >> 16) & 1u);
    return (unsigned short)(u >> 16);
}
__device__ __forceinline__ float bf16_f(unsigned short h) {
    unsigned u = ((unsigned)h) << 16;
    return __builtin_bit_cast(float, u);
}
// packed {lo:hi} bf16 split of v: low16 = bf16_rne(v), high16 = bf16_rne(v - hi)
__device__ __forceinline__ unsigned pk_hl(float v) {
    unsigned a, p;
    const float z = 0.0f;
    asm("v_cvt_pk_bf16_f32 %0, %1, %2" : "=v"(a) : "v"(v), "v"(z));
    const float hif = __builtin_bit_cast(float, a << 16);
    const float d = v - hif;
    asm("v_cvt_pk_bf16_f32 %0, %1, %2" : "=v"(p) : "v"(v), "v"(d));
    return p;
}
__device__ __forceinline__ float sig_f(float v) {
    return __builtin_amdgcn_rcpf(1.0f + __expf(-v));
}
__device__ __forceinline__ float tanh_f(float v) {
    return 2.0f * __builtin_amdgcn_rcpf(1.0f + __expf(-2.0f * v)) - 1.0f;
}

#define FENCE() __asm volatile("" ::: "memory")
#define WR32(arrp, sidx, val) (*(unsigned*)&(arrp)[(sidx)] = (val))

// one macro-iteration: computes cell1(T) and cell0(T+1) for 32 samples.
// P holds x(T+2) (issued one iteration ago); Q receives x(T+3) issue.
#define BODY(P, Q, T) do {                                                    \
    _Pragma("unroll")                                                         \
    for (int mh = 0; mh < 2; ++mh) {                                          \
        _Pragma("unroll")                                                     \
        for (int c = 0; c < 2; ++c)                                           \
            A1f[mh][c] = *(const short8*)&uA1w[(16 * mh + lm) * 72 + 32 * c + 8 * q]; \
        _Pragma("unroll")                                                     \
        for (int c = 0; c < 4; ++c)                                           \
            A0f[mh][c] = *(const short8*)&uA0w[(16 * mh + lm) * 136 + 32 * c + 8 * q]; \
    }                                                                         \
    FENCE();                                                                  \
    if ((T) < TSTEPS - 3) {                                                   \
        _Pragma("unroll")                                                     \
        for (int i = 0; i < NX; ++i) { xoff[i] += DDIM; Q[i] = x[xoff[i]]; }  \
    }                                                                         \
    f32x4 C[2][4], D[2][4];                                                   \
    _Pragma("unroll")                                                         \
    for (int mh = 0; mh < 2; ++mh) {                                          \
        _Pragma("unroll")                                                     \
        for (int T4 = 0; T4 < 4; ++T4) {                                      \
            f32x4 accD = {bias1[T4], bias1[T4], bias1[T4], bias1[T4]};        \
            _Pragma("unroll")                                                 \
            for (int c = 0; c < 2; ++c)                                       \
                accD = __builtin_amdgcn_mfma_f32_16x16x32_bf16(A1f[mh][c], B1[T4][c], accD, 0, 0, 0); \
            D[mh][T4] = accD;                                                 \
            f32x4 accC = {bias0[T4], bias0[T4], bias0[T4], bias0[T4]};        \
            _Pragma("unroll")                                                 \
            for (int c = 0; c < 4; ++c)                                       \
                accC = __builtin_amdgcn_mfma_f32_16x16x32_bf16(A0f[mh][c], B0[T4][c], accC, 0, 0, 0); \
            C[mh][T4] = accC;                                                 \
        }                                                                     \
    }                                                                         \
    _Pragma("unroll")                                                         \
    for (int mh = 0; mh < 2; ++mh) {                                          \
        _Pragma("unroll")                                                     \
        for (int r = 0; r < 4; ++r) {                                         \
            const float i1 = sig_f(D[mh][0][r]);                              \
            const float f1 = sig_f(D[mh][1][r]);                              \
            const float g1 = tanh_f(D[mh][2][r]);                             \
            const float o1 = sig_f(D[mh][3][r]);                              \
            const float c1 = f1 * c1s[mh][r] + i1 * g1;                       \
            c1s[mh][r] = c1;                                                  \
            h1v[mh][r] = o1 * tanh_f(c1);                                     \
            const float i0 = sig_f(C[mh][0][r]);                              \
            const float f0 = sig_f(C[mh][1][r]);                              \
            const float g0 = tanh_f(C[mh][2][r]);                             \
            const float o0 = sig_f(C[mh][3][r]);                              \
            const float c0 = f0 * c0s[mh][r] + i0 * g0;                       \
            c0s[mh][r] = c0;                                                  \
            h0v[mh][r] = o0 * tanh_f(c0);                                     \
        }                                                                     \
    }                                                                         \
    if ((T) < TSTEPS - 2) {                                                   \
        _Pragma("unroll")                                                     \
        for (int i = 0; i < NX; ++i) {                                        \
            const unsigned p = pk_hl(P[i]);                                   \
            WR32(uA0w, lofsA[i], p);                                          \
            uA0w[lofsB[i]] = (unsigned short)p;                               \
        }                                                                     \
    }                                                                         \
    if (lm < 10) {                                                            \
        _Pragma("unroll")                                                     \
        for (int mh = 0; mh < 2; ++mh) {                                      \
            _Pragma("unroll")                                                 \
            for (int r = 0; r < 4; ++r) {                                     \
                const int m = 16 * mh + 4 * q + r;                            \
                const unsigned p1 = pk_hl(h1v[mh][r]);                        \
                unsigned short* r1 = &uA1w[m * 72];                           \
                WR32(r1, 20 + 2 * lm, p1); r1[50 + lm] = (unsigned short)p1;  \
                const unsigned p0 = pk_hl(h0v[mh][r]);                        \
                WR32(r1, 2 * lm, p0);      r1[40 + lm] = (unsigned short)p0;  \
                unsigned short* r0 = &uA0w[m * 136];                          \
                WR32(r0, 56 + 2 * lm, p0); r0[104 + lm] = (unsigned short)p0; \
            }                                                                 \
        }                                                                     \
    }                                                                         \
    FENCE();                                                                  \
} while (0)

__global__ __launch_bounds__(128, 1) void lstm2_mfma_kernel(
    const float* __restrict__ x,
    const float* __restrict__ w_ih0, const float* __restrict__ w_hh0,
    const float* __restrict__ b_ih0, const float* __restrict__ b_hh0,
    const float* __restrict__ w_ih1, const float* __restrict__ w_hh1,
    const float* __restrict__ b_ih1, const float* __restrict__ b_hh1,
    const float* __restrict__ w_cls, const float* __restrict__ b_cls,
    float* __restrict__ out)
{
    // 2 independent waves per block; per-wave private LDS; no barriers.
    // A0 row (stride 136 shorts): [ (x_d hi,lo) pairs d<28 : cols 0..55 |
    //   (h0_u hi,lo) pairs u<10 : 56..75 | x_d hi : 76..103 |
    //   h0_u hi : 104..113 | pad 114..135 ]   -- 32 rows (2 M-tiles)
    // A1 row (stride 72): [ (h0 hi,lo) 0..19 | (h1 hi,lo) 20..39 |
    //   h0 hi 40..49 | h1 hi 50..59 | pad 60..71 ] -- 32 rows
    __shared__ __align__(16) unsigned short uA0s[2][32 * 136];
    __shared__ __align__(16) unsigned short uA1s[2][32 * 72];
    __shared__ __align__(16) float hfins[2][32 * 12];

    const int l   = threadIdx.x & 63;
    const int wid = threadIdx.x >> 6;
    const int lm  = l & 15;
    const int q   = l >> 4;
    const int sbase = (blockIdx.x * 2 + wid) * 32;

    unsigned short* const uA0w = uA0s[wid];
    unsigned short* const uA1w = uA1s[wid];
    float* const hfinw = hfins[wid];

    // ---- zero A-panel pads (NaN*0=NaN in MFMA) ----
    for (int i = l; i < 32 * 22; i += 64) uA0w[(i / 22) * 136 + 114 + (i % 22)] = 0;
    for (int i = l; i < 32 * 12; i += 64) uA1w[(i / 12) * 72 + 60 + (i % 12)] = 0;

    // ---- build B-fragments in registers (once; shared by both M-tiles) ----
    // 4 N-tiles: tile T row lm = gate g = 10T+lm (lm<10; rows lm>=10 zero).
    // T=0:i, T=1:f, T=2:g, T=3:o (torch gate order).
    // B0 k-zones: kk<76 pair zone -> w_hi (j2=kk>>1); [76,114) -> w_lo.
    // B1 k-zones: kk<40 pair zone -> w_hi; [40,60) -> w_lo.
    short8 B0[4][4], B1[4][2];
    const bool gvalid = (lm < 10);
    #pragma unroll
    for (int T = 0; T < 4; ++T) {
        const int g = 10 * T + lm;
        #pragma unroll
        for (int c = 0; c < 4; ++c) {
            #pragma unroll
            for (int j = 0; j < 8; ++j) {
                const int kk = 32 * c + 8 * q + j;
                unsigned short bits = 0;
                if (gvalid && kk < 114) {
                    if (kk < 76) {
                        const int j2 = kk >> 1;
                        const float w = (j2 < 28) ? w_ih0[g * 28 + j2]
                                                  : w_hh0[g * 10 + (j2 - 28)];
                        bits = bf16_rne(w);
                    } else {
                        const int d = kk - 76;
                        const float w = (d < 28) ? w_ih0[g * 28 + d]
                                                 : w_hh0[g * 10 + (d - 28)];
                        const unsigned short hi = bf16_rne(w);
                        bits = bf16_rne(w - bf16_f(hi));
                    }
                }
                B0[T][c][j] = (short)bits;
            }
        }
        #pragma unroll
        for (int c = 0; c < 2; ++c) {
            #pragma unroll
            for (int j = 0; j < 8; ++j) {
                const int kk = 32 * c + 8 * q + j;
                unsigned short bits = 0;
                if (gvalid && kk < 60) {
                    if (kk < 40) {
                        const int j2 = kk >> 1;
                        const float w = (j2 < 10) ? w_ih1[g * 10 + j2]
                                                  : w_hh1[g * 10 + (j2 - 10)];
                        bits = bf16_rne(w);
                    } else {
                        const int d = kk - 40;
                        const float w = (d < 10) ? w_ih1[g * 10 + d]
                                                 : w_hh1[g * 10 + (d - 10)];
                        const unsigned short hi = bf16_rne(w);
                        bits = bf16_rne(w - bf16_f(hi));
                    }
                }
                B1[T][c][j] = (short)bits;
            }
        }
    }

    // biases folded into MFMA C-init
    float bias0[4], bias1[4];
    #pragma unroll
    for (int T = 0; T < 4; ++T) {
        const int g = 10 * T + lm;
        bias0[T] = gvalid ? (b_ih0[g] + b_hh0[g]) : 0.0f;
        bias1[T] = gvalid ? (b_ih1[g] + b_hh1[g]) : 0.0f;
    }

    // ---- x pipeline: lane owns NX=14 of the wave's 896 (sample,d) elems ----
    int xoff[NX], lofsA[NX], lofsB[NX];
    float xA[NX], xB[NX];
    #pragma unroll
    for (int i = 0; i < NX; ++i) {
        const int f = l + 64 * i;
        const int sm = f / 28, d = f - 28 * sm;
        lofsA[i] = sm * 136 + 2 * d;        // b32 (pair zone)
        lofsB[i] = sm * 136 + 76 + d;       // b16 (hi zone)
        xoff[i] = (sbase + sm) * (TSTEPS * DDIM) + d;
        xA[i] = x[xoff[i]];                 // t = 0
    }
    #pragma unroll
    for (int i = 0; i < NX; ++i) {
        const unsigned p = pk_hl(xA[i]);
        WR32(uA0w, lofsA[i], p);
        uA0w[lofsB[i]] = (unsigned short)p;
    }
    // zero h zones (h0 = h1 = 0 at t=0)
    if (lm < 10) {
        #pragma unroll
        for (int mh = 0; mh < 2; ++mh) {
            #pragma unroll
            for (int r = 0; r < 4; ++r) {
                const int m = 16 * mh + 4 * q + r;
                unsigned short* r0 = &uA0w[m * 136];
                WR32(r0, 56 + 2 * lm, 0u); r0[104 + lm] = 0;
                unsigned short* r1 = &uA1w[m * 72];
                WR32(r1, 2 * lm, 0u);      r1[40 + lm] = 0;   // h0
                WR32(r1, 20 + 2 * lm, 0u); r1[50 + lm] = 0;   // h1
            }
        }
    }
    FENCE();

    float c0s[2][4] = {{0,0,0,0},{0,0,0,0}}, c1s[2][4] = {{0,0,0,0},{0,0,0,0}};
    float h1v[2][4] = {{0,0,0,0},{0,0,0,0}};
    float h0v[2][4];
    short8 A0f[2][4], A1f[2][2];

    // issue x(1) -> xA (consumed at end of prologue)
    #pragma unroll
    for (int i = 0; i < NX; ++i) { xoff[i] += DDIM; xA[i] = x[xoff[i]]; }

    // ================= prologue: cell0(0) =================
    #pragma unroll
    for (int mh = 0; mh < 2; ++mh)
        #pragma unroll
        for (int c = 0; c < 4; ++c)
            A0f[mh][c] = *(const short8*)&uA0w[(16 * mh + lm) * 136 + 32 * c + 8 * q];
    FENCE();
    // issue x(2) -> xB (consumed in main-loop body t=0)
    #pragma unroll
    for (int i = 0; i < NX; ++i) { xoff[i] += DDIM; xB[i] = x[xoff[i]]; }
    {
        f32x4 C[2][4];
        #pragma unroll
        for (int mh = 0; mh < 2; ++mh) {
            #pragma unroll
            for (int T = 0; T < 4; ++T) {
                f32x4 acc = {bias0[T], bias0[T], bias0[T], bias0[T]};
                #pragma unroll
                for (int c = 0; c < 4; ++c)
                    acc = __builtin_amdgcn_mfma_f32_16x16x32_bf16(A0f[mh][c], B0[T][c], acc, 0, 0, 0);
                C[mh][T] = acc;
            }
        }
        #pragma unroll
        for (int mh = 0; mh < 2; ++mh) {
            #pragma unroll
            for (int r = 0; r < 4; ++r) {
                const float i0 = sig_f(C[mh][0][r]);
                const float f0 = sig_f(C[mh][1][r]);
                const float g0 = tanh_f(C[mh][2][r]);
                const float o0 = sig_f(C[mh][3][r]);
                const float c0 = f0 * c0s[mh][r] + i0 * g0;
                c0s[mh][r] = c0;
                h0v[mh][r] = o0 * tanh_f(c0);
            }
        }
        if (lm < 10) {
            #pragma unroll
            for (int mh = 0; mh < 2; ++mh) {
                #pragma unroll
                for (int r = 0; r < 4; ++r) {
                    const int m = 16 * mh + 4 * q + r;
                    const unsigned p0 = pk_hl(h0v[mh][r]);
                    unsigned short* r0 = &uA0w[m * 136];
                    WR32(r0, 56 + 2 * lm, p0); r0[104 + lm] = (unsigned short)p0;
                    unsigned short* r1 = &uA1w[m * 72];
                    WR32(r1, 2 * lm, p0);      r1[40 + lm] = (unsigned short)p0;
                }
            }
        }
        // write x(1) (xA loads issued well before)
        #pragma unroll
        for (int i = 0; i < NX; ++i) {
            const unsigned p = pk_hl(xA[i]);
            WR32(uA0w, lofsA[i], p);
            uA0w[lofsB[i]] = (unsigned short)p;
        }
    }
    FENCE();

    // ===== main loop: body t computes cell1(t) and cell0(t+1); x buffers
    // alternate roles so each load is consumed one full iteration later =====
    #pragma unroll 1
    for (int tp = 0; tp < 13; ++tp) {
        BODY(xB, xA, 2 * tp);
        BODY(xA, xB, 2 * tp + 1);
    }
    BODY(xB, xA, 26);

    // ================= epilogue: cell1(27), all in registers =================
    {
        #pragma unroll
        for (int mh = 0; mh < 2; ++mh)
            #pragma unroll
            for (int c = 0; c < 2; ++c)
                A1f[mh][c] = *(const short8*)&uA1w[(16 * mh + lm) * 72 + 32 * c + 8 * q];
        FENCE();
        f32x4 D[2][4];
        #pragma unroll
        for (int mh = 0; mh < 2; ++mh) {
            #pragma unroll
            for (int T = 0; T < 4; ++T) {
                f32x4 acc = {bias1[T], bias1[T], bias1[T], bias1[T]};
                #pragma unroll
                for (int c = 0; c < 2; ++c)
                    acc = __builtin_amdgcn_mfma_f32_16x16x32_bf16(A1f[mh][c], B1[T][c], acc, 0, 0, 0);
                D[mh][T] = acc;
            }
        }
        #pragma unroll
        for (int mh = 0; mh < 2; ++mh) {
            #pragma unroll
            for (int r = 0; r < 4; ++r) {
                const float i1 = sig_f(D[mh][0][r]);
                const float f1 = sig_f(D[mh][1][r]);
                const float g1 = tanh_f(D[mh][2][r]);
                const float o1 = sig_f(D[mh][3][r]);
                const float c1 = f1 * c1s[mh][r] + i1 * g1;
                h1v[mh][r] = o1 * tanh_f(c1);
            }
        }
    }

    // ---- classifier ----
    if (lm < 10) {
        #pragma unroll
        for (int mh = 0; mh < 2; ++mh)
            #pragma unroll
            for (int r = 0; r < 4; ++r)
                hfinw[(16 * mh + 4 * q + r) * 12 + lm] = h1v[mh][r];
    }
    FENCE();
    if (lm < 10) {
        float wc[10];
        #pragma unroll
        for (int j = 0; j < 10; ++j) wc[j] = w_cls[lm * 10 + j];
        const float bo = b_cls[lm];
        #pragma unroll
        for (int mh = 0; mh < 2; ++mh) {
            #pragma unroll
            for (int r = 0; r < 4; ++r) {
                const int m = 16 * mh + 4 * q + r;
                float acc = bo;
                #pragma unroll
                for (int j = 0; j < 10; ++j) acc += hfinw[m * 12 + j] * wc[j];
                out[(size_t)(sbase + m) * 10 + lm] = acc;
            }
        }
    }
}

extern "C" void kernel_launch(void* const* d_in, const int* in_sizes, int n_in,
                              void* d_out, int out_size, void* d_ws, size_t ws_size,
                              hipStream_t stream) {
    const float* x     = (const float*)d_in[0];
    const float* w_ih0 = (const float*)d_in[1];
    const float* w_hh0 = (const float*)d_in[2];
    const float* b_ih0 = (const float*)d_in[3];
    const float* b_hh0 = (const float*)d_in[4];
    const float* w_ih1 = (const float*)d_in[5];
    const float* w_hh1 = (const float*)d_in[6];
    const float* b_ih1 = (const float*)d_in[7];
    const float* b_hh1 = (const float*)d_in[8];
    const float* w_cls = (const float*)d_in[9];
    const float* b_cls = (const float*)d_in[10];
    float* out = (float*)d_out;

    const int B = in_sizes[0] / (TSTEPS * DDIM);   // 32768
    const int grid = B / 64;                       // 512 blocks x 2 waves x 32 samples

    hipLaunchKernelGGL(lstm2_mfma_kernel, dim3(grid), dim3(128), 0, stream,
                       x, w_ih0, w_hh0, b_ih0, b_hh0,
                       w_ih1, w_hh1, b_ih1, b_hh1,
                       w_cls, b_cls, out);
}